// Round 8
// baseline (3680.770 us; speedup 1.0000x reference)
//
#include <hip/hip_runtime.h>
#include <hip/hip_bf16.h>

#define B_ 128
#define T_ 256
#define TA_ 8
#define E_ 512
#define H_ 512
#define D_ 1024
#define G3_ 1536
#define TC_ 16
#define NCH_ 16

#define HPAD_ 520      // 520 % 32 == 8 -> staggered h reads conflict-free
#define RPAD_ 776      // 776 % 32 == 8 -> reduction access <=2-way (free)
#define SMEM_FLOATS_ (16 * HPAD_ + 16 * RPAD_)
#define SMEM_BYTES_ (SMEM_FLOATS_ * sizeof(float))

// barrier layout: 8 groups x 32 slots, each slot padded to 32 uints (128 B)
#define SLOT_STRIDE_ 32
#define SLOTS_UINTS_ (8 * 32 * SLOT_STRIDE_)

__device__ __forceinline__ float sigmoidf_(float x) { return 1.0f / (1.0f + __expf(-x)); }

// ---- transpose w_hh (512 x 1536) -> w_hhT (1536 x 512) -------------------
__global__ __launch_bounds__(256) void k_transpose(const float* __restrict__ w, float* __restrict__ wt) {
  __shared__ float tile[32][33];
  const int tx = threadIdx.x & 31, ty = threadIdx.x >> 5;
  const int c0 = blockIdx.x * 32, i0 = blockIdx.y * 32;
#pragma unroll
  for (int r = 0; r < 4; ++r) {
    int ii = ty + r * 8;
    tile[ii][tx] = w[(size_t)(i0 + ii) * G3_ + c0 + tx];
  }
  __syncthreads();
#pragma unroll
  for (int r = 0; r < 4; ++r) {
    int cc = ty + r * 8;
    wt[(size_t)(c0 + cc) * H_ + i0 + tx] = tile[tx][cc];
  }
}

// ---- aspect mean pooling --------------------------------------------------
__global__ __launch_bounds__(256) void k_asp_pool(const int* __restrict__ aidx, const float* __restrict__ embed,
                                                  float* __restrict__ ap) {
  const int b = blockIdx.x;
  int ai[TA_]; int cnt = 0;
#pragma unroll
  for (int ta = 0; ta < TA_; ++ta) { ai[ta] = aidx[b * TA_ + ta]; cnt += (ai[ta] != 0); }
  const float inv = 1.0f / (float)cnt;
  for (int e = threadIdx.x; e < E_; e += 256) {
    float s = 0.f;
#pragma unroll
    for (int ta = 0; ta < TA_; ++ta) s += embed[(size_t)ai[ta] * E_ + e];
    ap[b * E_ + e] = s * inv;
  }
}

// ---- y[d] = sum_j v[j] * W[j][d] (+ bias) ---------------------------------
__global__ __launch_bounds__(256) void k_matvecT(const float* __restrict__ v, const float* __restrict__ W,
                                                 const float* __restrict__ bias, float* __restrict__ y,
                                                 int J, int N) {
  __shared__ float v_s[1024];
  for (int i = threadIdx.x; i < J; i += 256) v_s[i] = v[i];
  __syncthreads();
  const int d = blockIdx.x * 256 + threadIdx.x;
  float acc = bias ? bias[d] : 0.f;
  for (int j = 0; j < J; j += 4) {
    acc += v_s[j + 0] * W[(size_t)(j + 0) * N + d];
    acc += v_s[j + 1] * W[(size_t)(j + 1) * N + d];
    acc += v_s[j + 2] * W[(size_t)(j + 2) * N + d];
    acc += v_s[j + 3] * W[(size_t)(j + 3) * N + d];
  }
  y[d] = acc;
}

// ---- u[k] = sum_d wk_w[k][d] * qw[d], k < 512 ------------------------------
__global__ __launch_bounds__(256) void k_u(const float* __restrict__ wk, const float* __restrict__ qw,
                                           float* __restrict__ u) {
  __shared__ float q_s[D_];
  for (int i = threadIdx.x; i < D_; i += 256) q_s[i] = qw[i];
  __syncthreads();
  const int lane = threadIdx.x & 63, wave = threadIdx.x >> 6;
  const int k = blockIdx.x * 4 + wave;
  float p = 0.f;
#pragma unroll
  for (int m = 0; m < 16; ++m) { int d = lane + m * 64; p += wk[(size_t)k * D_ + d] * q_s[d]; }
#pragma unroll
  for (int off = 32; off > 0; off >>= 1) p += __shfl_down(p, off);
  if (lane == 0) u[k] = p;
}

// ---- ag[b][g] = asp_pool[b] @ w_ih[:E] + b_gru ------------------------------
__global__ __launch_bounds__(256) void k_ag(const float* __restrict__ ap, const float* __restrict__ w_ih,
                                            const float* __restrict__ bg, float* __restrict__ ag) {
  __shared__ float a_s[4][E_];
  const int g0 = blockIdx.x * 256, b0 = blockIdx.y * 4;
#pragma unroll
  for (int r = 0; r < 2; ++r) {
    int li = threadIdx.x + r * 256;
    int row = li >> 7, c4 = (li & 127) * 4;
    *(float4*)&a_s[row][c4] = *(const float4*)&ap[(size_t)(b0 + row) * E_ + c4];
  }
  __syncthreads();
  const int g = g0 + threadIdx.x;
  float acc0 = 0.f, acc1 = 0.f, acc2 = 0.f, acc3 = 0.f;
  for (int i4 = 0; i4 < 128; ++i4) {
    const float* wp = &w_ih[(size_t)(i4 * 4) * G3_ + g];
    float w0 = wp[0], w1 = wp[G3_], w2 = wp[2 * G3_], w3 = wp[3 * G3_];
    float4 a0 = *(const float4*)&a_s[0][i4 * 4];
    float4 a1 = *(const float4*)&a_s[1][i4 * 4];
    float4 a2 = *(const float4*)&a_s[2][i4 * 4];
    float4 a3 = *(const float4*)&a_s[3][i4 * 4];
    acc0 += a0.x * w0 + a0.y * w1 + a0.z * w2 + a0.w * w3;
    acc1 += a1.x * w0 + a1.y * w1 + a1.z * w2 + a1.w * w3;
    acc2 += a2.x * w0 + a2.y * w1 + a2.z * w2 + a2.w * w3;
    acc3 += a3.x * w0 + a3.y * w1 + a3.z * w2 + a3.w * w3;
  }
  const float bgv = bg[g];
  ag[(size_t)(b0 + 0) * G3_ + g] = acc0 + bgv;
  ag[(size_t)(b0 + 1) * G3_ + g] = acc1 + bgv;
  ag[(size_t)(b0 + 2) * G3_ + g] = acc2 + bgv;
  ag[(size_t)(b0 + 3) * G3_ + g] = acc3 + bgv;
}

// ---- xg chunk GEMM: C[m][g] = gathered_x[m] @ w_ih[E:2E] + ag[b] -----------
__global__ __launch_bounds__(256) void k_gemm_xg(const int* __restrict__ tidx, const float* __restrict__ embed,
                                                 const float* __restrict__ w_ih, const float* __restrict__ ag,
                                                 float* __restrict__ xg, int chunk) {
  __shared__ float A_s[16][68];
  __shared__ float B_s[16][68];
  const int tid = threadIdx.x;
  const int g0 = blockIdx.x * 64, m0 = blockIdx.y * 64;
  const int tx = tid & 15, ty = tid >> 4;
  float acc[4][4] = {};

  const int ar = tid >> 2, akq = (tid & 3) * 4;
  const int am = m0 + ar;
  const int ab = am >> 4;
  const int at = chunk * TC_ + (am & 15);
  const int tix = tidx[ab * T_ + at];
  const float* aptr = embed + (size_t)tix * E_ + akq;
  const float amask = (tix != 0) ? 1.f : 0.f;

  const int bkk = tid >> 4, bgq = (tid & 15) * 4;
  const float* bptr = w_ih + (size_t)(E_ + bkk) * G3_ + g0 + bgq;

  for (int k0 = 0; k0 < E_; k0 += 16) {
    float4 av = *(const float4*)(aptr + k0);
    av.x *= amask; av.y *= amask; av.z *= amask; av.w *= amask;
    A_s[akq + 0][ar] = av.x; A_s[akq + 1][ar] = av.y;
    A_s[akq + 2][ar] = av.z; A_s[akq + 3][ar] = av.w;
    *(float4*)&B_s[bkk][bgq] = *(const float4*)(bptr + (size_t)k0 * G3_);
    __syncthreads();
#pragma unroll
    for (int kk = 0; kk < 16; ++kk) {
      float4 a  = *(const float4*)&A_s[kk][ty * 4];
      float4 bv = *(const float4*)&B_s[kk][tx * 4];
      acc[0][0] += a.x * bv.x; acc[0][1] += a.x * bv.y; acc[0][2] += a.x * bv.z; acc[0][3] += a.x * bv.w;
      acc[1][0] += a.y * bv.x; acc[1][1] += a.y * bv.y; acc[1][2] += a.y * bv.z; acc[1][3] += a.y * bv.w;
      acc[2][0] += a.z * bv.x; acc[2][1] += a.z * bv.y; acc[2][2] += a.z * bv.z; acc[2][3] += a.z * bv.w;
      acc[3][0] += a.w * bv.x; acc[3][1] += a.w * bv.y; acc[3][2] += a.w * bv.z; acc[3][3] += a.w * bv.w;
    }
    __syncthreads();
  }
#pragma unroll
  for (int i = 0; i < 4; ++i) {
    int m = m0 + ty * 4 + i;
    int b = m >> 4;
    float4 agv = *(const float4*)&ag[(size_t)b * G3_ + g0 + tx * 4];
    float4 o;
    o.x = acc[i][0] + agv.x; o.y = acc[i][1] + agv.y;
    o.z = acc[i][2] + agv.z; o.w = acc[i][3] + agv.w;
    *(float4*)&xg[(size_t)m * G3_ + g0 + tx * 4] = o;
  }
}

// ---- persistent GRU chunk: 1024 threads (4 waves/SIMD), weights in regs ----
// grid = 256 blocks: kg = bid>>3, bg = bid&7. Threads: ig = tid>>4 (64
// K-segments of 8), tx = tid&15 (column). Per thread: W[3][8][1 col] =
// 24 floats in VGPRs; acc live set 24 (two batch-halves of 8).
// Within each wave, the 4 ig-groups pre-reduce 4:1 via __shfl_down, so only
// 16 wave-rows of partials hit LDS (red_s 48.5 KB; total LDS 81 KB -> one
// 1024-thread block/CU = 4 waves/SIMD for latency hiding).
// Sync identical to rounds 4-7 (relaxed agent atomics, parallel slot poll).
__global__ __launch_bounds__(1024, 4) void k_gru_chunk(const float* __restrict__ whhT,
                                                       const float* __restrict__ xg,
                                                       float* __restrict__ hA, float* __restrict__ hB,
                                                       float* __restrict__ hs,
                                                       unsigned int* __restrict__ slots,
                                                       int chunk) {
  extern __shared__ float smem[];
  float* h_s   = smem;                 // 16 x HPAD_
  float* red_s = smem + 16 * HPAD_;    // 16 x RPAD_   [wave][b*48 + gate*16 + tx]
  const int tid = threadIdx.x;
  const int kg = blockIdx.x >> 3;
  const int bg = blockIdx.x & 7;
  const int k0 = kg * 16, b0 = bg * 16;
  const int tx = tid & 15, ig = tid >> 4;   // ig 0..63
  const int i0 = ig * 8;
  const int wv = tid >> 6;                  // wave 0..15
  const int lane = tid & 63;

  // ---- load this thread's weights into registers (once per chunk) ----------
  float4 wR[2], wZ[2], wN[2];
#pragma unroll
  for (int s = 0; s < 2; ++s) {
    const int jj = i0 + s * 4;
    wR[s] = *(const float4*)&whhT[(size_t)(0 * H_ + k0 + tx) * H_ + jj];
    wZ[s] = *(const float4*)&whhT[(size_t)(1 * H_ + k0 + tx) * H_ + jj];
    wN[s] = *(const float4*)&whhT[(size_t)(2 * H_ + k0 + tx) * H_ + jj];
  }

  unsigned int* myslot   = slots + (bg * 32 + kg) * SLOT_STRIDE_;
  unsigned int* grpslots = slots + bg * 32 * SLOT_STRIDE_;
  const int gb = tid >> 4;          // gate-math batch row (valid for tid<256)

  for (int tc = 0; tc < TC_; ++tc) {
    const int t = chunk * TC_ + tc;
    const float* hprev = (t & 1) ? hB : hA;
    float*       hnext = (t & 1) ? hA : hB;

    // hoisted xg loads (independent of h -> overlap staging latency)
    float xr = 0.f, xz = 0.f, xn = 0.f;
    if (tid < 256) {
      const float* xrow = xg + ((size_t)(b0 + gb) * TC_ + tc) * G3_;
      const int k = k0 + tx;
      xr = xrow[k]; xz = xrow[H_ + k]; xn = xrow[2 * H_ + k];
    }

    // stage h tile (16 x 512) via relaxed agent 8B atomic loads (4/thread)
#pragma unroll
    for (int ii = 0; ii < 4; ++ii) {
      const int li = tid + ii * 1024;       // 4096 u64 total
      const int r = li >> 8, c2 = (li & 255) << 1;
      const unsigned long long v =
          __hip_atomic_load((const unsigned long long*)&hprev[(size_t)(b0 + r) * H_ + c2],
                            __ATOMIC_RELAXED, __HIP_MEMORY_SCOPE_AGENT);
      *(unsigned long long*)&h_s[r * HPAD_ + c2] = v;
    }
    __syncthreads();

    // ---- accumulate partials, two batch-halves of 8 (24 live acc regs);
    //      4:1 in-wave shfl pre-reduction, lanes<16 write one row per wave ---
#pragma unroll
    for (int bh = 0; bh < 2; ++bh) {
      float accR[8], accZ[8], accN[8];
#pragma unroll
      for (int b = 0; b < 8; ++b) { accR[b] = 0.f; accZ[b] = 0.f; accN[b] = 0.f; }
#pragma unroll
      for (int s = 0; s < 2; ++s) {
        const int col = i0 + s * 4;
        const float4 wr4 = wR[s], wz4 = wZ[s], wn4 = wN[s];
#pragma unroll
        for (int b = 0; b < 8; ++b) {
          const float4 h4 = *(const float4*)&h_s[(bh * 8 + b) * HPAD_ + col];
          accR[b] += h4.x * wr4.x + h4.y * wr4.y + h4.z * wr4.z + h4.w * wr4.w;
          accZ[b] += h4.x * wz4.x + h4.y * wz4.y + h4.z * wz4.z + h4.w * wz4.w;
          accN[b] += h4.x * wn4.x + h4.y * wn4.y + h4.z * wn4.z + h4.w * wn4.w;
        }
      }
#pragma unroll
      for (int b = 0; b < 8; ++b) {
        float r = accR[b]; r += __shfl_down(r, 32); r += __shfl_down(r, 16);
        float z = accZ[b]; z += __shfl_down(z, 32); z += __shfl_down(z, 16);
        float n = accN[b]; n += __shfl_down(n, 32); n += __shfl_down(n, 16);
        if (lane < 16) {
          float* wp = &red_s[wv * RPAD_ + (bh * 8 + b) * 48];
          wp[0 * 16 + tx] = r;
          wp[1 * 16 + tx] = z;
          wp[2 * 16 + tx] = n;
        }
      }
    }
    float hp = 0.f;
    if (tid < 256) hp = h_s[gb * HPAD_ + k0 + tx];
    __syncthreads();

    // ---- reduce 16 wave-rows + gate math (tid<256: b=gb, col=tx) -----------
    if (tid < 256) {
      float sR = 0.f, sZ = 0.f, sN = 0.f;
#pragma unroll
      for (int w = 0; w < 16; ++w) {
        const float* rp = &red_s[w * RPAD_ + gb * 48];
        sR += rp[tx];
        sZ += rp[16 + tx];
        sN += rp[32 + tx];
      }
      const float gr = sigmoidf_(xr + sR);
      const float gz = sigmoidf_(xz + sZ);
      const float gn = tanhf(xn + gr * sN);
      const float hv = (1.f - gz) * gn + gz * hp;
      const int k = k0 + tx;
      __hip_atomic_store(&hnext[(size_t)(b0 + gb) * H_ + k], hv,
                         __ATOMIC_RELAXED, __HIP_MEMORY_SCOPE_AGENT);
      hs[((size_t)(b0 + gb) * T_ + t) * H_ + k] = hv;
    }

    __syncthreads();                      // drains vmcnt: h stores acked at IF
    if (tid == 0) {
      __hip_atomic_store(myslot, (unsigned int)(t + 1),
                         __ATOMIC_RELAXED, __HIP_MEMORY_SCOPE_AGENT);
    }
    if (tid < 32) {
      unsigned int* ps = grpslots + tid * SLOT_STRIDE_;
      while (__hip_atomic_load(ps, __ATOMIC_RELAXED, __HIP_MEMORY_SCOPE_AGENT)
             < (unsigned int)(t + 1)) {
        __builtin_amdgcn_s_sleep(1);
      }
    }
    __syncthreads();
  }
}

// ---- logits[b][t] = hs[b][t] . u -------------------------------------------
__global__ __launch_bounds__(256) void k_logits(const float* __restrict__ hs, const float* __restrict__ u,
                                                float* __restrict__ lg) {
  __shared__ float u_s[H_];
  for (int i = threadIdx.x; i < H_; i += 256) u_s[i] = u[i];
  __syncthreads();
  const int lane = threadIdx.x & 63, wave = threadIdx.x >> 6;
  const int wid = blockIdx.x * 4 + wave;
  const float* hrow = hs + (size_t)wid * H_;
  float p = 0.f;
#pragma unroll
  for (int m = 0; m < 8; ++m) { int d = lane + m * 64; p += hrow[d] * u_s[d]; }
#pragma unroll
  for (int off = 32; off > 0; off >>= 1) p += __shfl_down(p, off);
  if (lane == 0) lg[wid] = p;
}

// ---- softmax over t + weighted pooling -------------------------------------
__global__ __launch_bounds__(256) void k_softmax_pool(const float* __restrict__ lg, const float* __restrict__ hs,
                                                      float* __restrict__ pooled) {
  __shared__ float sw[256];
  __shared__ float red[8];
  const int b = blockIdx.x, tid = threadIdx.x;
  const int lane = tid & 63, wave = tid >> 6;
  const float lv = lg[b * T_ + tid];
  float mx = lv;
#pragma unroll
  for (int off = 32; off > 0; off >>= 1) mx = fmaxf(mx, __shfl_down(mx, off));
  if (lane == 0) red[wave] = mx;
  __syncthreads();
  if (tid == 0) red[4] = fmaxf(fmaxf(red[0], red[1]), fmaxf(red[2], red[3]));
  __syncthreads();
  mx = red[4];
  const float p = __expf(lv - mx);
  float sm = p;
#pragma unroll
  for (int off = 32; off > 0; off >>= 1) sm += __shfl_down(sm, off);
  if (lane == 0) red[wave] = sm;
  __syncthreads();
  if (tid == 0) red[5] = red[0] + red[1] + red[2] + red[3];
  __syncthreads();
  sw[tid] = p / red[5];
  __syncthreads();
  float a0 = 0.f, a1 = 0.f;
  const float* hbase = hs + (size_t)b * T_ * H_;
  for (int t = 0; t < T_; ++t) {
    const float s = sw[t];
    a0 += s * hbase[(size_t)t * H_ + tid];
    a1 += s * hbase[(size_t)t * H_ + 256 + tid];
  }
  pooled[b * H_ + tid] = a0;
  pooled[b * H_ + 256 + tid] = a1;
}

// ---- final dense (H->3) ----------------------------------------------------
__global__ __launch_bounds__(64) void k_dense(const float* __restrict__ pooled, const float* __restrict__ dw,
                                              const float* __restrict__ db, float* __restrict__ out) {
  const int b = blockIdx.x, lane = threadIdx.x;
  float a0 = 0.f, a1 = 0.f, a2 = 0.f;
#pragma unroll
  for (int m = 0; m < 8; ++m) {
    int h = lane + m * 64;
    float pv = pooled[b * H_ + h];
    a0 += pv * dw[h * 3 + 0];
    a1 += pv * dw[h * 3 + 1];
    a2 += pv * dw[h * 3 + 2];
  }
#pragma unroll
  for (int off = 32; off > 0; off >>= 1) {
    a0 += __shfl_down(a0, off);
    a1 += __shfl_down(a1, off);
    a2 += __shfl_down(a2, off);
  }
  if (lane == 0) {
    out[b * 3 + 0] = a0 + db[0];
    out[b * 3 + 1] = a1 + db[1];
    out[b * 3 + 2] = a2 + db[2];
  }
}

extern "C" void kernel_launch(void* const* d_in, const int* in_sizes, int n_in,
                              void* d_out, int out_size, void* d_ws, size_t ws_size,
                              hipStream_t stream) {
  (void)in_sizes; (void)n_in; (void)out_size; (void)ws_size;
  const int*   tidx  = (const int*)d_in[0];
  const int*   aidx  = (const int*)d_in[1];
  const float* embed = (const float*)d_in[2];
  const float* w_ih  = (const float*)d_in[3];
  const float* w_hh  = (const float*)d_in[4];
  const float* b_gru = (const float*)d_in[5];
  const float* wk_w  = (const float*)d_in[6];
  // d_in[7] = wk_b: cancels in softmax, unused
  const float* wq_w  = (const float*)d_in[8];
  const float* wq_b  = (const float*)d_in[9];
  const float* q_p   = (const float*)d_in[10];
  const float* bil_w = (const float*)d_in[11];
  const float* dw    = (const float*)d_in[12];
  const float* db    = (const float*)d_in[13];
  float* out = (float*)d_out;

  float* ws = (float*)d_ws;
  size_t off = 0;
  unsigned int* slots = (unsigned int*)(ws + off); off += SLOTS_UINTS_;
  float* ap     = ws + off; off += (size_t)B_ * E_;
  float* ag     = ws + off; off += (size_t)B_ * G3_;
  float* qx     = ws + off; off += D_;
  float* qw     = ws + off; off += D_;
  float* u      = ws + off; off += H_;
  float* hA     = ws + off; off += (size_t)B_ * H_;
  float* hB     = ws + off; off += (size_t)B_ * H_;
  float* lg     = ws + off; off += (size_t)B_ * T_;
  float* pooled = ws + off; off += (size_t)B_ * H_;
  float* whhT   = ws + off; off += (size_t)G3_ * H_;
  float* xgbuf  = ws + off; off += (size_t)B_ * TC_ * G3_;
  float* hs     = ws + off; off += (size_t)B_ * T_ * H_;

  hipFuncSetAttribute((const void*)k_gru_chunk, hipFuncAttributeMaxDynamicSharedMemorySize,
                      (int)SMEM_BYTES_);

  hipMemsetAsync(slots, 0, SLOTS_UINTS_ * sizeof(unsigned int), stream);
  hipMemsetAsync(hA, 0, (size_t)B_ * H_ * sizeof(float), stream);

  k_transpose<<<dim3(48, 16), 256, 0, stream>>>(w_hh, whhT);
  k_asp_pool<<<B_, 256, 0, stream>>>(aidx, embed, ap);
  k_matvecT<<<4, 256, 0, stream>>>(q_p, wq_w, wq_b, qx, D_, D_);
  k_matvecT<<<4, 256, 0, stream>>>(qx, bil_w, nullptr, qw, D_, D_);
  k_u<<<128, 256, 0, stream>>>(wk_w, qw, u);
  k_ag<<<dim3(6, 32), 256, 0, stream>>>(ap, w_ih, b_gru, ag);

  for (int chunk = 0; chunk < NCH_; ++chunk) {
    k_gemm_xg<<<dim3(24, 32), 256, 0, stream>>>(tidx, embed, w_ih, ag, xgbuf, chunk);
    int ch = chunk;
    void* args[] = { (void*)&whhT, (void*)&xgbuf, (void*)&hA, (void*)&hB,
                     (void*)&hs, (void*)&slots, (void*)&ch };
    hipLaunchCooperativeKernel((const void*)k_gru_chunk, dim3(256), dim3(1024),
                               args, (unsigned int)SMEM_BYTES_, stream);
  }

  k_logits<<<8192, 256, 0, stream>>>(hs, u, lg);
  k_softmax_pool<<<B_, 256, 0, stream>>>(lg, hs, pooled);
  k_dense<<<B_, 64, 0, stream>>>(pooled, dw, db, out);
}

// Round 9
// 3324.509 us; speedup vs baseline: 1.1072x; 1.1072x over previous
//
#include <hip/hip_runtime.h>
#include <hip/hip_bf16.h>

#define B_ 128
#define T_ 256
#define TA_ 8
#define E_ 512
#define H_ 512
#define D_ 1024
#define G3_ 1536
#define TC_ 16
#define NCH_ 16

#define HPAD_ 520      // 520 % 32 == 8 -> staggered h reads conflict-free
#define RPAD_ 776      // 776 % 32 == 8 -> reduction access <=2-way (free)
#define SMEM_FLOATS_ (16 * HPAD_ + 32 * RPAD_)
#define SMEM_BYTES_ (SMEM_FLOATS_ * sizeof(float))

__device__ __forceinline__ float sigmoidf_(float x) { return 1.0f / (1.0f + __expf(-x)); }

// ---- transpose w_hh (512 x 1536) -> w_hhT (1536 x 512) -------------------
__global__ __launch_bounds__(256) void k_transpose(const float* __restrict__ w, float* __restrict__ wt) {
  __shared__ float tile[32][33];
  const int tx = threadIdx.x & 31, ty = threadIdx.x >> 5;
  const int c0 = blockIdx.x * 32, i0 = blockIdx.y * 32;
#pragma unroll
  for (int r = 0; r < 4; ++r) {
    int ii = ty + r * 8;
    tile[ii][tx] = w[(size_t)(i0 + ii) * G3_ + c0 + tx];
  }
  __syncthreads();
#pragma unroll
  for (int r = 0; r < 4; ++r) {
    int cc = ty + r * 8;
    wt[(size_t)(c0 + cc) * H_ + i0 + tx] = tile[tx][cc];
  }
}

// ---- aspect mean pooling --------------------------------------------------
__global__ __launch_bounds__(256) void k_asp_pool(const int* __restrict__ aidx, const float* __restrict__ embed,
                                                  float* __restrict__ ap) {
  const int b = blockIdx.x;
  int ai[TA_]; int cnt = 0;
#pragma unroll
  for (int ta = 0; ta < TA_; ++ta) { ai[ta] = aidx[b * TA_ + ta]; cnt += (ai[ta] != 0); }
  const float inv = 1.0f / (float)cnt;
  for (int e = threadIdx.x; e < E_; e += 256) {
    float s = 0.f;
#pragma unroll
    for (int ta = 0; ta < TA_; ++ta) s += embed[(size_t)ai[ta] * E_ + e];
    ap[b * E_ + e] = s * inv;
  }
}

// ---- y[d] = sum_j v[j] * W[j][d] (+ bias) ---------------------------------
__global__ __launch_bounds__(256) void k_matvecT(const float* __restrict__ v, const float* __restrict__ W,
                                                 const float* __restrict__ bias, float* __restrict__ y,
                                                 int J, int N) {
  __shared__ float v_s[1024];
  for (int i = threadIdx.x; i < J; i += 256) v_s[i] = v[i];
  __syncthreads();
  const int d = blockIdx.x * 256 + threadIdx.x;
  float acc = bias ? bias[d] : 0.f;
  for (int j = 0; j < J; j += 4) {
    acc += v_s[j + 0] * W[(size_t)(j + 0) * N + d];
    acc += v_s[j + 1] * W[(size_t)(j + 1) * N + d];
    acc += v_s[j + 2] * W[(size_t)(j + 2) * N + d];
    acc += v_s[j + 3] * W[(size_t)(j + 3) * N + d];
  }
  y[d] = acc;
}

// ---- u[k] = sum_d wk_w[k][d] * qw[d], k < 512 ------------------------------
__global__ __launch_bounds__(256) void k_u(const float* __restrict__ wk, const float* __restrict__ qw,
                                           float* __restrict__ u) {
  __shared__ float q_s[D_];
  for (int i = threadIdx.x; i < D_; i += 256) q_s[i] = qw[i];
  __syncthreads();
  const int lane = threadIdx.x & 63, wave = threadIdx.x >> 6;
  const int k = blockIdx.x * 4 + wave;
  float p = 0.f;
#pragma unroll
  for (int m = 0; m < 16; ++m) { int d = lane + m * 64; p += wk[(size_t)k * D_ + d] * q_s[d]; }
#pragma unroll
  for (int off = 32; off > 0; off >>= 1) p += __shfl_down(p, off);
  if (lane == 0) u[k] = p;
}

// ---- ag[b][g] = asp_pool[b] @ w_ih[:E] + b_gru ------------------------------
__global__ __launch_bounds__(256) void k_ag(const float* __restrict__ ap, const float* __restrict__ w_ih,
                                            const float* __restrict__ bg, float* __restrict__ ag) {
  __shared__ float a_s[4][E_];
  const int g0 = blockIdx.x * 256, b0 = blockIdx.y * 4;
#pragma unroll
  for (int r = 0; r < 2; ++r) {
    int li = threadIdx.x + r * 256;
    int row = li >> 7, c4 = (li & 127) * 4;
    *(float4*)&a_s[row][c4] = *(const float4*)&ap[(size_t)(b0 + row) * E_ + c4];
  }
  __syncthreads();
  const int g = g0 + threadIdx.x;
  float acc0 = 0.f, acc1 = 0.f, acc2 = 0.f, acc3 = 0.f;
  for (int i4 = 0; i4 < 128; ++i4) {
    const float* wp = &w_ih[(size_t)(i4 * 4) * G3_ + g];
    float w0 = wp[0], w1 = wp[G3_], w2 = wp[2 * G3_], w3 = wp[3 * G3_];
    float4 a0 = *(const float4*)&a_s[0][i4 * 4];
    float4 a1 = *(const float4*)&a_s[1][i4 * 4];
    float4 a2 = *(const float4*)&a_s[2][i4 * 4];
    float4 a3 = *(const float4*)&a_s[3][i4 * 4];
    acc0 += a0.x * w0 + a0.y * w1 + a0.z * w2 + a0.w * w3;
    acc1 += a1.x * w0 + a1.y * w1 + a1.z * w2 + a1.w * w3;
    acc2 += a2.x * w0 + a2.y * w1 + a2.z * w2 + a2.w * w3;
    acc3 += a3.x * w0 + a3.y * w1 + a3.z * w2 + a3.w * w3;
  }
  const float bgv = bg[g];
  ag[(size_t)(b0 + 0) * G3_ + g] = acc0 + bgv;
  ag[(size_t)(b0 + 1) * G3_ + g] = acc1 + bgv;
  ag[(size_t)(b0 + 2) * G3_ + g] = acc2 + bgv;
  ag[(size_t)(b0 + 3) * G3_ + g] = acc3 + bgv;
}

// ---- xg chunk GEMM: C[m][g] = gathered_x[m] @ w_ih[E:2E] + ag[b] -----------
__global__ __launch_bounds__(256) void k_gemm_xg(const int* __restrict__ tidx, const float* __restrict__ embed,
                                                 const float* __restrict__ w_ih, const float* __restrict__ ag,
                                                 float* __restrict__ xg, int chunk) {
  __shared__ float A_s[16][68];
  __shared__ float B_s[16][68];
  const int tid = threadIdx.x;
  const int g0 = blockIdx.x * 64, m0 = blockIdx.y * 64;
  const int tx = tid & 15, ty = tid >> 4;
  float acc[4][4] = {};

  const int ar = tid >> 2, akq = (tid & 3) * 4;
  const int am = m0 + ar;
  const int ab = am >> 4;
  const int at = chunk * TC_ + (am & 15);
  const int tix = tidx[ab * T_ + at];
  const float* aptr = embed + (size_t)tix * E_ + akq;
  const float amask = (tix != 0) ? 1.f : 0.f;

  const int bkk = tid >> 4, bgq = (tid & 15) * 4;
  const float* bptr = w_ih + (size_t)(E_ + bkk) * G3_ + g0 + bgq;

  for (int k0 = 0; k0 < E_; k0 += 16) {
    float4 av = *(const float4*)(aptr + k0);
    av.x *= amask; av.y *= amask; av.z *= amask; av.w *= amask;
    A_s[akq + 0][ar] = av.x; A_s[akq + 1][ar] = av.y;
    A_s[akq + 2][ar] = av.z; A_s[akq + 3][ar] = av.w;
    *(float4*)&B_s[bkk][bgq] = *(const float4*)(bptr + (size_t)k0 * G3_);
    __syncthreads();
#pragma unroll
    for (int kk = 0; kk < 16; ++kk) {
      float4 a  = *(const float4*)&A_s[kk][ty * 4];
      float4 bv = *(const float4*)&B_s[kk][tx * 4];
      acc[0][0] += a.x * bv.x; acc[0][1] += a.x * bv.y; acc[0][2] += a.x * bv.z; acc[0][3] += a.x * bv.w;
      acc[1][0] += a.y * bv.x; acc[1][1] += a.y * bv.y; acc[1][2] += a.y * bv.z; acc[1][3] += a.y * bv.w;
      acc[2][0] += a.z * bv.x; acc[2][1] += a.z * bv.y; acc[2][2] += a.z * bv.z; acc[2][3] += a.z * bv.w;
      acc[3][0] += a.w * bv.x; acc[3][1] += a.w * bv.y; acc[3][2] += a.w * bv.z; acc[3][3] += a.w * bv.w;
    }
    __syncthreads();
  }
#pragma unroll
  for (int i = 0; i < 4; ++i) {
    int m = m0 + ty * 4 + i;
    int b = m >> 4;
    float4 agv = *(const float4*)&ag[(size_t)b * G3_ + g0 + tx * 4];
    float4 o;
    o.x = acc[i][0] + agv.x; o.y = acc[i][1] + agv.y;
    o.z = acc[i][2] + agv.z; o.w = acc[i][3] + agv.w;
    *(float4*)&xg[(size_t)m * G3_ + g0 + tx * 4] = o;
  }
}

// ---- persistent GRU chunk: TAGGED DATA-FLOW sync (no barrier) ---------------
// grid = 256 blocks: kg = bid>>3, bg = bid&7; 512 threads (round-7 compute).
// h is exchanged as atomic u64 {tag=version<<32 | f32 bits} in ping-pong
// buffers. Consumers poll tag == t directly -> ONE IF round-trip per step
// (vs h-store + slot-store + poll). Producer publishes h(t+1) only after
// fully staging h(t), so ping-pong overwrite is race-free (monotone tags).
// 2 syncthreads/step (LDS visibility only). Safe across graph replays:
// both buffers memset each launch; stale values would be bit-identical.
__global__ __launch_bounds__(512, 2) void k_gru_chunk(const float* __restrict__ whhT,
                                                      const float* __restrict__ xg,
                                                      unsigned long long* __restrict__ hA,
                                                      unsigned long long* __restrict__ hB,
                                                      float* __restrict__ hs,
                                                      int chunk) {
  extern __shared__ float smem[];
  float* h_s   = smem;                 // 16 x HPAD_
  float* red_s = smem + 16 * HPAD_;    // 32 x RPAD_   [ig][b*48 + gate*16 + tx]
  const int tid = threadIdx.x;
  const int kg = blockIdx.x >> 3;
  const int bg = blockIdx.x & 7;
  const int k0 = kg * 16, b0 = bg * 16;
  const int tx = tid & 15, ig = tid >> 4;   // ig 0..31
  const int i0 = ig * 16;

  // ---- weights in registers (once per chunk) --------------------------------
  float4 wR[4], wZ[4], wN[4];
#pragma unroll
  for (int s = 0; s < 4; ++s) {
    const int jj = i0 + (((s + ig) & 3) << 2);
    wR[s] = *(const float4*)&whhT[(size_t)(0 * H_ + k0 + tx) * H_ + jj];
    wZ[s] = *(const float4*)&whhT[(size_t)(1 * H_ + k0 + tx) * H_ + jj];
    wN[s] = *(const float4*)&whhT[(size_t)(2 * H_ + k0 + tx) * H_ + jj];
  }

  const int gb = tid >> 4;          // gate-math batch row (valid for tid<256)

  for (int tc = 0; tc < TC_; ++tc) {
    const int t = chunk * TC_ + tc;
    const unsigned long long* hsrc = (t & 1) ? hB : hA;
    unsigned long long*       hdst = (t & 1) ? hA : hB;
    const unsigned tagc = (unsigned)t;

    // hoisted xg loads (independent of h -> overlap poll latency)
    float xr = 0.f, xz = 0.f, xn = 0.f;
    if (tid < 256) {
      const float* xrow = xg + ((size_t)(b0 + gb) * TC_ + tc) * G3_;
      const int k = k0 + tx;
      xr = xrow[k]; xz = xrow[H_ + k]; xn = xrow[2 * H_ + k];
    }

    // ---- tagged staging: thread owns column c=tid across 16 batch rows.
    //      Two 8-wide poll batches: issue all loads, then check/re-poll. ------
#pragma unroll
    for (int half = 0; half < 2; ++half) {
      unsigned long long v[8];
#pragma unroll
      for (int ii = 0; ii < 8; ++ii)
        v[ii] = __hip_atomic_load(&hsrc[(size_t)(b0 + half * 8 + ii) * H_ + tid],
                                  __ATOMIC_RELAXED, __HIP_MEMORY_SCOPE_AGENT);
      unsigned pend = 0xFFu;
      while (pend) {
#pragma unroll
        for (int ii = 0; ii < 8; ++ii) {
          if ((pend >> ii) & 1u) {
            if ((unsigned)(v[ii] >> 32) == tagc) {
              union { unsigned u; float f; } cv;
              cv.u = (unsigned)(v[ii] & 0xFFFFFFFFull);
              h_s[(half * 8 + ii) * HPAD_ + tid] = cv.f;
              pend &= ~(1u << ii);
            } else {
              v[ii] = __hip_atomic_load(&hsrc[(size_t)(b0 + half * 8 + ii) * H_ + tid],
                                        __ATOMIC_RELAXED, __HIP_MEMORY_SCOPE_AGENT);
            }
          }
        }
        if (pend) __builtin_amdgcn_s_sleep(1);
      }
    }
    __syncthreads();

    // ---- accumulate partials, two batch-halves of 8 (24 live acc regs) ------
#pragma unroll
    for (int bh = 0; bh < 2; ++bh) {
      float accR[8], accZ[8], accN[8];
#pragma unroll
      for (int b = 0; b < 8; ++b) { accR[b] = 0.f; accZ[b] = 0.f; accN[b] = 0.f; }
#pragma unroll
      for (int s = 0; s < 4; ++s) {
        const int col = i0 + (((s + ig) & 3) << 2);
        const float4 wr4 = wR[s], wz4 = wZ[s], wn4 = wN[s];
#pragma unroll
        for (int b = 0; b < 8; ++b) {
          const float4 h4 = *(const float4*)&h_s[(bh * 8 + b) * HPAD_ + col];
          accR[b] += h4.x * wr4.x + h4.y * wr4.y + h4.z * wr4.z + h4.w * wr4.w;
          accZ[b] += h4.x * wz4.x + h4.y * wz4.y + h4.z * wz4.z + h4.w * wz4.w;
          accN[b] += h4.x * wn4.x + h4.y * wn4.y + h4.z * wn4.z + h4.w * wn4.w;
        }
      }
#pragma unroll
      for (int b = 0; b < 8; ++b) {
        float* wp = &red_s[ig * RPAD_ + (bh * 8 + b) * 48];
        wp[0 * 16 + tx] = accR[b];
        wp[1 * 16 + tx] = accZ[b];
        wp[2 * 16 + tx] = accN[b];
      }
    }
    float hp = 0.f;
    if (tid < 256) hp = h_s[gb * HPAD_ + k0 + tx];
    __syncthreads();

    // ---- reduce 32 segments + gate math (tid<256: b=gb, col=tx) -------------
    if (tid < 256) {
      float sR = 0.f, sZ = 0.f, sN = 0.f;
#pragma unroll
      for (int g16 = 0; g16 < 32; ++g16) {
        const float* rp = &red_s[g16 * RPAD_ + gb * 48];
        sR += rp[tx];
        sZ += rp[16 + tx];
        sN += rp[32 + tx];
      }
      const float gr = sigmoidf_(xr + sR);
      const float gz = sigmoidf_(xz + sZ);
      const float gn = tanhf(xn + gr * sN);
      const float hv = (1.f - gz) * gn + gz * hp;
      const int k = k0 + tx;
      union { float f; unsigned u; } cv; cv.f = hv;
      __hip_atomic_store(&hdst[(size_t)(b0 + gb) * H_ + k],
                         ((unsigned long long)(unsigned)(t + 1) << 32) | (unsigned long long)cv.u,
                         __ATOMIC_RELAXED, __HIP_MEMORY_SCOPE_AGENT);
      hs[((size_t)(b0 + gb) * T_ + t) * H_ + k] = hv;
    }
    // no loop-end barrier: h_s/red_s hazards covered by the two syncthreads
    // (a thread can only reach the next step's writes after all threads passed
    //  this step's corresponding barrier).
  }
}

// ---- logits[b][t] = hs[b][t] . u -------------------------------------------
__global__ __launch_bounds__(256) void k_logits(const float* __restrict__ hs, const float* __restrict__ u,
                                                float* __restrict__ lg) {
  __shared__ float u_s[H_];
  for (int i = threadIdx.x; i < H_; i += 256) u_s[i] = u[i];
  __syncthreads();
  const int lane = threadIdx.x & 63, wave = threadIdx.x >> 6;
  const int wid = blockIdx.x * 4 + wave;
  const float* hrow = hs + (size_t)wid * H_;
  float p = 0.f;
#pragma unroll
  for (int m = 0; m < 8; ++m) { int d = lane + m * 64; p += hrow[d] * u_s[d]; }
#pragma unroll
  for (int off = 32; off > 0; off >>= 1) p += __shfl_down(p, off);
  if (lane == 0) lg[wid] = p;
}

// ---- softmax over t + weighted pooling -------------------------------------
__global__ __launch_bounds__(256) void k_softmax_pool(const float* __restrict__ lg, const float* __restrict__ hs,
                                                      float* __restrict__ pooled) {
  __shared__ float sw[256];
  __shared__ float red[8];
  const int b = blockIdx.x, tid = threadIdx.x;
  const int lane = tid & 63, wave = tid >> 6;
  const float lv = lg[b * T_ + tid];
  float mx = lv;
#pragma unroll
  for (int off = 32; off > 0; off >>= 1) mx = fmaxf(mx, __shfl_down(mx, off));
  if (lane == 0) red[wave] = mx;
  __syncthreads();
  if (tid == 0) red[4] = fmaxf(fmaxf(red[0], red[1]), fmaxf(red[2], red[3]));
  __syncthreads();
  mx = red[4];
  const float p = __expf(lv - mx);
  float sm = p;
#pragma unroll
  for (int off = 32; off > 0; off >>= 1) sm += __shfl_down(sm, off);
  if (lane == 0) red[wave] = sm;
  __syncthreads();
  if (tid == 0) red[5] = red[0] + red[1] + red[2] + red[3];
  __syncthreads();
  sw[tid] = p / red[5];
  __syncthreads();
  float a0 = 0.f, a1 = 0.f;
  const float* hbase = hs + (size_t)b * T_ * H_;
  for (int t = 0; t < T_; ++t) {
    const float s = sw[t];
    a0 += s * hbase[(size_t)t * H_ + tid];
    a1 += s * hbase[(size_t)t * H_ + 256 + tid];
  }
  pooled[b * H_ + tid] = a0;
  pooled[b * H_ + 256 + tid] = a1;
}

// ---- final dense (H->3) ----------------------------------------------------
__global__ __launch_bounds__(64) void k_dense(const float* __restrict__ pooled, const float* __restrict__ dw,
                                              const float* __restrict__ db, float* __restrict__ out) {
  const int b = blockIdx.x, lane = threadIdx.x;
  float a0 = 0.f, a1 = 0.f, a2 = 0.f;
#pragma unroll
  for (int m = 0; m < 8; ++m) {
    int h = lane + m * 64;
    float pv = pooled[b * H_ + h];
    a0 += pv * dw[h * 3 + 0];
    a1 += pv * dw[h * 3 + 1];
    a2 += pv * dw[h * 3 + 2];
  }
#pragma unroll
  for (int off = 32; off > 0; off >>= 1) {
    a0 += __shfl_down(a0, off);
    a1 += __shfl_down(a1, off);
    a2 += __shfl_down(a2, off);
  }
  if (lane == 0) {
    out[b * 3 + 0] = a0 + db[0];
    out[b * 3 + 1] = a1 + db[1];
    out[b * 3 + 2] = a2 + db[2];
  }
}

extern "C" void kernel_launch(void* const* d_in, const int* in_sizes, int n_in,
                              void* d_out, int out_size, void* d_ws, size_t ws_size,
                              hipStream_t stream) {
  (void)in_sizes; (void)n_in; (void)out_size; (void)ws_size;
  const int*   tidx  = (const int*)d_in[0];
  const int*   aidx  = (const int*)d_in[1];
  const float* embed = (const float*)d_in[2];
  const float* w_ih  = (const float*)d_in[3];
  const float* w_hh  = (const float*)d_in[4];
  const float* b_gru = (const float*)d_in[5];
  const float* wk_w  = (const float*)d_in[6];
  // d_in[7] = wk_b: cancels in softmax, unused
  const float* wq_w  = (const float*)d_in[8];
  const float* wq_b  = (const float*)d_in[9];
  const float* q_p   = (const float*)d_in[10];
  const float* bil_w = (const float*)d_in[11];
  const float* dw    = (const float*)d_in[12];
  const float* db    = (const float*)d_in[13];
  float* out = (float*)d_out;

  float* ws = (float*)d_ws;
  size_t off = 0;
  unsigned long long* hA64 = (unsigned long long*)(ws + off); off += (size_t)B_ * H_ * 2;
  unsigned long long* hB64 = (unsigned long long*)(ws + off); off += (size_t)B_ * H_ * 2;
  float* ap     = ws + off; off += (size_t)B_ * E_;
  float* ag     = ws + off; off += (size_t)B_ * G3_;
  float* qx     = ws + off; off += D_;
  float* qw     = ws + off; off += D_;
  float* u      = ws + off; off += H_;
  float* lg     = ws + off; off += (size_t)B_ * T_;
  float* pooled = ws + off; off += (size_t)B_ * H_;
  float* whhT   = ws + off; off += (size_t)G3_ * H_;
  float* xgbuf  = ws + off; off += (size_t)B_ * TC_ * G3_;
  float* hs     = ws + off; off += (size_t)B_ * T_ * H_;

  hipFuncSetAttribute((const void*)k_gru_chunk, hipFuncAttributeMaxDynamicSharedMemorySize,
                      (int)SMEM_BYTES_);

  // zero both tagged h buffers: hA supplies {h=0, tag=0} for step 0; clean
  // tags every launch make graph replays independent of leftover state.
  hipMemsetAsync(hA64, 0, (size_t)B_ * H_ * 2 * sizeof(unsigned long long), stream);

  k_transpose<<<dim3(48, 16), 256, 0, stream>>>(w_hh, whhT);
  k_asp_pool<<<B_, 256, 0, stream>>>(aidx, embed, ap);
  k_matvecT<<<4, 256, 0, stream>>>(q_p, wq_w, wq_b, qx, D_, D_);
  k_matvecT<<<4, 256, 0, stream>>>(qx, bil_w, nullptr, qw, D_, D_);
  k_u<<<128, 256, 0, stream>>>(wk_w, qw, u);
  k_ag<<<dim3(6, 32), 256, 0, stream>>>(ap, w_ih, b_gru, ag);

  for (int chunk = 0; chunk < NCH_; ++chunk) {
    k_gemm_xg<<<dim3(24, 32), 256, 0, stream>>>(tidx, embed, w_ih, ag, xgbuf, chunk);
    int ch = chunk;
    void* args[] = { (void*)&whhT, (void*)&xgbuf, (void*)&hA64, (void*)&hB64,
                     (void*)&hs, (void*)&ch };
    hipLaunchCooperativeKernel((const void*)k_gru_chunk, dim3(256), dim3(512),
                               args, (unsigned int)SMEM_BYTES_, stream);
  }

  k_logits<<<8192, 256, 0, stream>>>(hs, u, lg);
  k_softmax_pool<<<B_, 256, 0, stream>>>(lg, hs, pooled);
  k_dense<<<B_, 64, 0, stream>>>(pooled, dw, db, out);
}

// Round 10
// 2863.829 us; speedup vs baseline: 1.2853x; 1.1609x over previous
//
#include <hip/hip_runtime.h>
#include <hip/hip_bf16.h>

#define B_ 128
#define T_ 256
#define TA_ 8
#define E_ 512
#define H_ 512
#define D_ 1024
#define G3_ 1536
#define TC_ 16
#define NCH_ 16

typedef __attribute__((ext_vector_type(8))) short bf16x8_;
typedef __attribute__((ext_vector_type(4))) float f32x4_;

__device__ __forceinline__ float sigmoidf_(float x) { return 1.0f / (1.0f + __expf(-x)); }

__device__ __forceinline__ unsigned short f2bf_(float f) {
  unsigned u = __float_as_uint(f);
  return (unsigned short)((u + 0x7FFFu + ((u >> 16) & 1u)) >> 16);   // RNE
}
__device__ __forceinline__ float bf2f_(unsigned short b) {
  return __uint_as_float((unsigned)b << 16);
}

// ---- transpose w_hh (512 x 1536) -> w_hhT (1536 x 512) -------------------
__global__ __launch_bounds__(256) void k_transpose(const float* __restrict__ w, float* __restrict__ wt) {
  __shared__ float tile[32][33];
  const int tx = threadIdx.x & 31, ty = threadIdx.x >> 5;
  const int c0 = blockIdx.x * 32, i0 = blockIdx.y * 32;
#pragma unroll
  for (int r = 0; r < 4; ++r) {
    int ii = ty + r * 8;
    tile[ii][tx] = w[(size_t)(i0 + ii) * G3_ + c0 + tx];
  }
  __syncthreads();
#pragma unroll
  for (int r = 0; r < 4; ++r) {
    int cc = ty + r * 8;
    wt[(size_t)(c0 + cc) * H_ + i0 + tx] = tile[tx][cc];
  }
}

// ---- aspect mean pooling --------------------------------------------------
__global__ __launch_bounds__(256) void k_asp_pool(const int* __restrict__ aidx, const float* __restrict__ embed,
                                                  float* __restrict__ ap) {
  const int b = blockIdx.x;
  int ai[TA_]; int cnt = 0;
#pragma unroll
  for (int ta = 0; ta < TA_; ++ta) { ai[ta] = aidx[b * TA_ + ta]; cnt += (ai[ta] != 0); }
  const float inv = 1.0f / (float)cnt;
  for (int e = threadIdx.x; e < E_; e += 256) {
    float s = 0.f;
#pragma unroll
    for (int ta = 0; ta < TA_; ++ta) s += embed[(size_t)ai[ta] * E_ + e];
    ap[b * E_ + e] = s * inv;
  }
}

// ---- y[d] = sum_j v[j] * W[j][d] (+ bias) ---------------------------------
__global__ __launch_bounds__(256) void k_matvecT(const float* __restrict__ v, const float* __restrict__ W,
                                                 const float* __restrict__ bias, float* __restrict__ y,
                                                 int J, int N) {
  __shared__ float v_s[1024];
  for (int i = threadIdx.x; i < J; i += 256) v_s[i] = v[i];
  __syncthreads();
  const int d = blockIdx.x * 256 + threadIdx.x;
  float acc = bias ? bias[d] : 0.f;
  for (int j = 0; j < J; j += 4) {
    acc += v_s[j + 0] * W[(size_t)(j + 0) * N + d];
    acc += v_s[j + 1] * W[(size_t)(j + 1) * N + d];
    acc += v_s[j + 2] * W[(size_t)(j + 2) * N + d];
    acc += v_s[j + 3] * W[(size_t)(j + 3) * N + d];
  }
  y[d] = acc;
}

// ---- u[k] = sum_d wk_w[k][d] * qw[d], k < 512 ------------------------------
__global__ __launch_bounds__(256) void k_u(const float* __restrict__ wk, const float* __restrict__ qw,
                                           float* __restrict__ u) {
  __shared__ float q_s[D_];
  for (int i = threadIdx.x; i < D_; i += 256) q_s[i] = qw[i];
  __syncthreads();
  const int lane = threadIdx.x & 63, wave = threadIdx.x >> 6;
  const int k = blockIdx.x * 4 + wave;
  float p = 0.f;
#pragma unroll
  for (int m = 0; m < 16; ++m) { int d = lane + m * 64; p += wk[(size_t)k * D_ + d] * q_s[d]; }
#pragma unroll
  for (int off = 32; off > 0; off >>= 1) p += __shfl_down(p, off);
  if (lane == 0) u[k] = p;
}

// ---- ag[b][g] = asp_pool[b] @ w_ih[:E] + b_gru ------------------------------
__global__ __launch_bounds__(256) void k_ag(const float* __restrict__ ap, const float* __restrict__ w_ih,
                                            const float* __restrict__ bg, float* __restrict__ ag) {
  __shared__ float a_s[4][E_];
  const int g0 = blockIdx.x * 256, b0 = blockIdx.y * 4;
#pragma unroll
  for (int r = 0; r < 2; ++r) {
    int li = threadIdx.x + r * 256;
    int row = li >> 7, c4 = (li & 127) * 4;
    *(float4*)&a_s[row][c4] = *(const float4*)&ap[(size_t)(b0 + row) * E_ + c4];
  }
  __syncthreads();
  const int g = g0 + threadIdx.x;
  float acc0 = 0.f, acc1 = 0.f, acc2 = 0.f, acc3 = 0.f;
  for (int i4 = 0; i4 < 128; ++i4) {
    const float* wp = &w_ih[(size_t)(i4 * 4) * G3_ + g];
    float w0 = wp[0], w1 = wp[G3_], w2 = wp[2 * G3_], w3 = wp[3 * G3_];
    float4 a0 = *(const float4*)&a_s[0][i4 * 4];
    float4 a1 = *(const float4*)&a_s[1][i4 * 4];
    float4 a2 = *(const float4*)&a_s[2][i4 * 4];
    float4 a3 = *(const float4*)&a_s[3][i4 * 4];
    acc0 += a0.x * w0 + a0.y * w1 + a0.z * w2 + a0.w * w3;
    acc1 += a1.x * w0 + a1.y * w1 + a1.z * w2 + a1.w * w3;
    acc2 += a2.x * w0 + a2.y * w1 + a2.z * w2 + a2.w * w3;
    acc3 += a3.x * w0 + a3.y * w1 + a3.z * w2 + a3.w * w3;
  }
  const float bgv = bg[g];
  ag[(size_t)(b0 + 0) * G3_ + g] = acc0 + bgv;
  ag[(size_t)(b0 + 1) * G3_ + g] = acc1 + bgv;
  ag[(size_t)(b0 + 2) * G3_ + g] = acc2 + bgv;
  ag[(size_t)(b0 + 3) * G3_ + g] = acc3 + bgv;
}

// ---- xg chunk GEMM: C[m][g] = gathered_x[m] @ w_ih[E:2E] + ag[b] -----------
__global__ __launch_bounds__(256) void k_gemm_xg(const int* __restrict__ tidx, const float* __restrict__ embed,
                                                 const float* __restrict__ w_ih, const float* __restrict__ ag,
                                                 float* __restrict__ xg, int chunk) {
  __shared__ float A_s[16][68];
  __shared__ float B_s[16][68];
  const int tid = threadIdx.x;
  const int g0 = blockIdx.x * 64, m0 = blockIdx.y * 64;
  const int tx = tid & 15, ty = tid >> 4;
  float acc[4][4] = {};

  const int ar = tid >> 2, akq = (tid & 3) * 4;
  const int am = m0 + ar;
  const int ab = am >> 4;
  const int at = chunk * TC_ + (am & 15);
  const int tix = tidx[ab * T_ + at];
  const float* aptr = embed + (size_t)tix * E_ + akq;
  const float amask = (tix != 0) ? 1.f : 0.f;

  const int bkk = tid >> 4, bgq = (tid & 15) * 4;
  const float* bptr = w_ih + (size_t)(E_ + bkk) * G3_ + g0 + bgq;

  for (int k0 = 0; k0 < E_; k0 += 16) {
    float4 av = *(const float4*)(aptr + k0);
    av.x *= amask; av.y *= amask; av.z *= amask; av.w *= amask;
    A_s[akq + 0][ar] = av.x; A_s[akq + 1][ar] = av.y;
    A_s[akq + 2][ar] = av.z; A_s[akq + 3][ar] = av.w;
    *(float4*)&B_s[bkk][bgq] = *(const float4*)(bptr + (size_t)k0 * G3_);
    __syncthreads();
#pragma unroll
    for (int kk = 0; kk < 16; ++kk) {
      float4 a  = *(const float4*)&A_s[kk][ty * 4];
      float4 bv = *(const float4*)&B_s[kk][tx * 4];
      acc[0][0] += a.x * bv.x; acc[0][1] += a.x * bv.y; acc[0][2] += a.x * bv.z; acc[0][3] += a.x * bv.w;
      acc[1][0] += a.y * bv.x; acc[1][1] += a.y * bv.y; acc[1][2] += a.y * bv.z; acc[1][3] += a.y * bv.w;
      acc[2][0] += a.z * bv.x; acc[2][1] += a.z * bv.y; acc[2][2] += a.z * bv.z; acc[2][3] += a.z * bv.w;
      acc[3][0] += a.w * bv.x; acc[3][1] += a.w * bv.y; acc[3][2] += a.w * bv.z; acc[3][3] += a.w * bv.w;
    }
    __syncthreads();
  }
#pragma unroll
  for (int i = 0; i < 4; ++i) {
    int m = m0 + ty * 4 + i;
    int b = m >> 4;
    float4 agv = *(const float4*)&ag[(size_t)b * G3_ + g0 + tx * 4];
    float4 o;
    o.x = acc[i][0] + agv.x; o.y = acc[i][1] + agv.y;
    o.z = acc[i][2] + agv.z; o.w = acc[i][3] + agv.w;
    *(float4*)&xg[(size_t)m * G3_ + g0 + tx * 4] = o;
  }
}

// ---- persistent GRU chunk: MFMA split-bf16, tagged data-flow sync ----------
// grid = 256 blocks: kg = bid>>3, bg = bid&7; 512 threads (8 waves).
// Waves 0-5: (gate = wv>>1, K-half = wv&1). Each holds its weight B-fragments
// in VGPRs (pre-split bf16 hi/lo, 64 VGPR), built per m89-verified layout:
// lane l holds B[k=(l>>4)*8+j][col=l&15]; D: col=lane&15, row=(lane>>4)*4+reg.
// Per step: poll tagged h -> split to bf16 hi/lo in LDS (+exact f32 for own
// cols); 24 MFMA/wave (8 Ksteps x {hi*hi, hi*lo, lo*hi}); 2:1 C-combine in
// LDS; 256 gate threads finish. The old 393K-FMA accumulate + 32-way LDS
// reduction is gone. hexact race-free: each element's only reader is its own
// producer thread, and overwrite is gated by that producer's tagged store.
__global__ __launch_bounds__(512, 2) void k_gru_chunk(const float* __restrict__ whhT,
                                                      const float* __restrict__ xg,
                                                      unsigned long long* __restrict__ hA,
                                                      unsigned long long* __restrict__ hB,
                                                      float* __restrict__ hs,
                                                      int chunk) {
  __shared__ __align__(16) unsigned short h_hi_s[16 * 520];
  __shared__ __align__(16) unsigned short h_lo_s[16 * 520];
  __shared__ float hexact_s[16][16];
  __shared__ __align__(16) float cbuf_s[3][64][4];
  __shared__ float csum_s[3][16][17];

  const int tid = threadIdx.x;
  const int kg = blockIdx.x >> 3;
  const int bg = blockIdx.x & 7;
  const int k0 = kg * 16, b0 = bg * 16;
  const int lane = tid & 63, wv = tid >> 6;
  const int gate = wv >> 1, kseg = wv & 1;      // valid for wv<6
  const int lrow = lane & 15, lhi = lane >> 4;
  const int gb = tid >> 4, tx = tid & 15;       // gate-math map (tid<256)

  // ---- pre-split weight B-fragments into registers (once per chunk) --------
  bf16x8_ bhi[8], blo[8];
  if (wv < 6) {
    const float* wp = &whhT[((size_t)(gate * H_ + k0 + lrow)) * H_ + kseg * 256 + lhi * 8];
#pragma unroll
    for (int ks = 0; ks < 8; ++ks) {
      float fv[8];
      *(float4*)&fv[0] = *(const float4*)(wp + ks * 32);
      *(float4*)&fv[4] = *(const float4*)(wp + ks * 32 + 4);
      bf16x8_ h8, l8;
#pragma unroll
      for (int j = 0; j < 8; ++j) {
        const unsigned short hb = f2bf_(fv[j]);
        h8[j] = (short)hb;
        l8[j] = (short)f2bf_(fv[j] - bf2f_(hb));
      }
      bhi[ks] = h8; blo[ks] = l8;
    }
  }

  for (int tc = 0; tc < TC_; ++tc) {
    const int t = chunk * TC_ + tc;
    const unsigned long long* hsrc = (t & 1) ? hB : hA;
    unsigned long long*       hdst = (t & 1) ? hA : hB;
    const unsigned tagc = (unsigned)t;

    // hoisted xg loads (independent of h -> overlap poll latency)
    float xr = 0.f, xz = 0.f, xn = 0.f;
    if (tid < 256) {
      const float* xrow = xg + ((size_t)(b0 + gb) * TC_ + tc) * G3_;
      const int k = k0 + tx;
      xr = xrow[k]; xz = xrow[H_ + k]; xn = xrow[2 * H_ + k];
    }

    // ---- tagged staging: thread owns column tid across 16 rows; convert to
    //      split bf16 (hi/lo) + exact f32 for this block's own 16 columns ----
#pragma unroll
    for (int half = 0; half < 2; ++half) {
      unsigned long long v[8];
#pragma unroll
      for (int ii = 0; ii < 8; ++ii)
        v[ii] = __hip_atomic_load(&hsrc[(size_t)(b0 + half * 8 + ii) * H_ + tid],
                                  __ATOMIC_RELAXED, __HIP_MEMORY_SCOPE_AGENT);
      unsigned pend = 0xFFu;
      while (pend) {
#pragma unroll
        for (int ii = 0; ii < 8; ++ii) {
          if ((pend >> ii) & 1u) {
            if ((unsigned)(v[ii] >> 32) == tagc) {
              union { unsigned u; float f; } cv;
              cv.u = (unsigned)(v[ii] & 0xFFFFFFFFull);
              const int r = half * 8 + ii;
              const unsigned short hb = f2bf_(cv.f);
              h_hi_s[r * 520 + tid] = hb;
              h_lo_s[r * 520 + tid] = f2bf_(cv.f - bf2f_(hb));
              if ((unsigned)(tid - k0) < 16u) hexact_s[r][tid - k0] = cv.f;
              pend &= ~(1u << ii);
            } else {
              v[ii] = __hip_atomic_load(&hsrc[(size_t)(b0 + half * 8 + ii) * H_ + tid],
                                        __ATOMIC_RELAXED, __HIP_MEMORY_SCOPE_AGENT);
            }
          }
        }
        if (pend) __builtin_amdgcn_s_sleep(1);
      }
    }
    __syncthreads();

    // ---- MFMA phase: 8 Ksteps x 3 split-terms per active wave ---------------
    f32x4_ c = {0.f, 0.f, 0.f, 0.f};
    if (wv < 6) {
      const int abase = lrow * 520 + kseg * 256 + lhi * 8;
#pragma unroll
      for (int ks = 0; ks < 8; ++ks) {
        const bf16x8_ ahi = *(const bf16x8_*)&h_hi_s[abase + ks * 32];
        const bf16x8_ alo = *(const bf16x8_*)&h_lo_s[abase + ks * 32];
        c = __builtin_amdgcn_mfma_f32_16x16x32_bf16(ahi, bhi[ks], c, 0, 0, 0);
        c = __builtin_amdgcn_mfma_f32_16x16x32_bf16(ahi, blo[ks], c, 0, 0, 0);
        c = __builtin_amdgcn_mfma_f32_16x16x32_bf16(alo, bhi[ks], c, 0, 0, 0);
      }
      if (kseg == 1) *(f32x4_*)&cbuf_s[gate][lane][0] = c;
    }
    __syncthreads();

    // ---- 2:1 combine -> csum[gate][batch][col] ------------------------------
    if (wv < 6 && kseg == 0) {
      const f32x4_ c2 = *(const f32x4_*)&cbuf_s[gate][lane][0];
#pragma unroll
      for (int r = 0; r < 4; ++r)
        csum_s[gate][lhi * 4 + r][lrow] = c[r] + c2[r];
    }
    __syncthreads();

    // ---- gate math + tagged store (tid<256: b=gb, col=tx) -------------------
    if (tid < 256) {
      const float sR = csum_s[0][gb][tx];
      const float sZ = csum_s[1][gb][tx];
      const float sN = csum_s[2][gb][tx];
      const float hp = hexact_s[gb][tx];
      const float gr = sigmoidf_(xr + sR);
      const float gz = sigmoidf_(xz + sZ);
      const float gn = tanhf(xn + gr * sN);
      const float hv = (1.f - gz) * gn + gz * hp;
      const int k = k0 + tx;
      union { float f; unsigned u; } cv; cv.f = hv;
      __hip_atomic_store(&hdst[(size_t)(b0 + gb) * H_ + k],
                         ((unsigned long long)(unsigned)(t + 1) << 32) | (unsigned long long)cv.u,
                         __ATOMIC_RELAXED, __HIP_MEMORY_SCOPE_AGENT);
      hs[((size_t)(b0 + gb) * T_ + t) * H_ + k] = hv;
    }
    // loop: next staging's LDS writes are safe — every thread passed the
    // csum-ready barrier, and h/hexact overwrites are gated per-element by
    // the producer's tagged store (see header comment).
  }
}

// ---- logits[b][t] = hs[b][t] . u -------------------------------------------
__global__ __launch_bounds__(256) void k_logits(const float* __restrict__ hs, const float* __restrict__ u,
                                                float* __restrict__ lg) {
  __shared__ float u_s[H_];
  for (int i = threadIdx.x; i < H_; i += 256) u_s[i] = u[i];
  __syncthreads();
  const int lane = threadIdx.x & 63, wave = threadIdx.x >> 6;
  const int wid = blockIdx.x * 4 + wave;
  const float* hrow = hs + (size_t)wid * H_;
  float p = 0.f;
#pragma unroll
  for (int m = 0; m < 8; ++m) { int d = lane + m * 64; p += hrow[d] * u_s[d]; }
#pragma unroll
  for (int off = 32; off > 0; off >>= 1) p += __shfl_down(p, off);
  if (lane == 0) lg[wid] = p;
}

// ---- softmax over t + weighted pooling -------------------------------------
__global__ __launch_bounds__(256) void k_softmax_pool(const float* __restrict__ lg, const float* __restrict__ hs,
                                                      float* __restrict__ pooled) {
  __shared__ float sw[256];
  __shared__ float red[8];
  const int b = blockIdx.x, tid = threadIdx.x;
  const int lane = tid & 63, wave = tid >> 6;
  const float lv = lg[b * T_ + tid];
  float mx = lv;
#pragma unroll
  for (int off = 32; off > 0; off >>= 1) mx = fmaxf(mx, __shfl_down(mx, off));
  if (lane == 0) red[wave] = mx;
  __syncthreads();
  if (tid == 0) red[4] = fmaxf(fmaxf(red[0], red[1]), fmaxf(red[2], red[3]));
  __syncthreads();
  mx = red[4];
  const float p = __expf(lv - mx);
  float sm = p;
#pragma unroll
  for (int off = 32; off > 0; off >>= 1) sm += __shfl_down(sm, off);
  if (lane == 0) red[wave] = sm;
  __syncthreads();
  if (tid == 0) red[5] = red[0] + red[1] + red[2] + red[3];
  __syncthreads();
  sw[tid] = p / red[5];
  __syncthreads();
  float a0 = 0.f, a1 = 0.f;
  const float* hbase = hs + (size_t)b * T_ * H_;
  for (int t = 0; t < T_; ++t) {
    const float s = sw[t];
    a0 += s * hbase[(size_t)t * H_ + tid];
    a1 += s * hbase[(size_t)t * H_ + 256 + tid];
  }
  pooled[b * H_ + tid] = a0;
  pooled[b * H_ + 256 + tid] = a1;
}

// ---- final dense (H->3) ----------------------------------------------------
__global__ __launch_bounds__(64) void k_dense(const float* __restrict__ pooled, const float* __restrict__ dw,
                                              const float* __restrict__ db, float* __restrict__ out) {
  const int b = blockIdx.x, lane = threadIdx.x;
  float a0 = 0.f, a1 = 0.f, a2 = 0.f;
#pragma unroll
  for (int m = 0; m < 8; ++m) {
    int h = lane + m * 64;
    float pv = pooled[b * H_ + h];
    a0 += pv * dw[h * 3 + 0];
    a1 += pv * dw[h * 3 + 1];
    a2 += pv * dw[h * 3 + 2];
  }
#pragma unroll
  for (int off = 32; off > 0; off >>= 1) {
    a0 += __shfl_down(a0, off);
    a1 += __shfl_down(a1, off);
    a2 += __shfl_down(a2, off);
  }
  if (lane == 0) {
    out[b * 3 + 0] = a0 + db[0];
    out[b * 3 + 1] = a1 + db[1];
    out[b * 3 + 2] = a2 + db[2];
  }
}

extern "C" void kernel_launch(void* const* d_in, const int* in_sizes, int n_in,
                              void* d_out, int out_size, void* d_ws, size_t ws_size,
                              hipStream_t stream) {
  (void)in_sizes; (void)n_in; (void)out_size; (void)ws_size;
  const int*   tidx  = (const int*)d_in[0];
  const int*   aidx  = (const int*)d_in[1];
  const float* embed = (const float*)d_in[2];
  const float* w_ih  = (const float*)d_in[3];
  const float* w_hh  = (const float*)d_in[4];
  const float* b_gru = (const float*)d_in[5];
  const float* wk_w  = (const float*)d_in[6];
  // d_in[7] = wk_b: cancels in softmax, unused
  const float* wq_w  = (const float*)d_in[8];
  const float* wq_b  = (const float*)d_in[9];
  const float* q_p   = (const float*)d_in[10];
  const float* bil_w = (const float*)d_in[11];
  const float* dw    = (const float*)d_in[12];
  const float* db    = (const float*)d_in[13];
  float* out = (float*)d_out;

  float* ws = (float*)d_ws;
  size_t off = 0;
  unsigned long long* hA64 = (unsigned long long*)(ws + off); off += (size_t)B_ * H_ * 2;
  unsigned long long* hB64 = (unsigned long long*)(ws + off); off += (size_t)B_ * H_ * 2;
  float* ap     = ws + off; off += (size_t)B_ * E_;
  float* ag     = ws + off; off += (size_t)B_ * G3_;
  float* qx     = ws + off; off += D_;
  float* qw     = ws + off; off += D_;
  float* u      = ws + off; off += H_;
  float* lg     = ws + off; off += (size_t)B_ * T_;
  float* pooled = ws + off; off += (size_t)B_ * H_;
  float* whhT   = ws + off; off += (size_t)G3_ * H_;
  float* xgbuf  = ws + off; off += (size_t)B_ * TC_ * G3_;
  float* hs     = ws + off; off += (size_t)B_ * T_ * H_;

  // zero both tagged h buffers: hA supplies {h=0, tag=0} for step 0; clean
  // tags every launch make graph replays independent of leftover state.
  hipMemsetAsync(hA64, 0, (size_t)B_ * H_ * 2 * sizeof(unsigned long long), stream);

  k_transpose<<<dim3(48, 16), 256, 0, stream>>>(w_hh, whhT);
  k_asp_pool<<<B_, 256, 0, stream>>>(aidx, embed, ap);
  k_matvecT<<<4, 256, 0, stream>>>(q_p, wq_w, wq_b, qx, D_, D_);
  k_matvecT<<<4, 256, 0, stream>>>(qx, bil_w, nullptr, qw, D_, D_);
  k_u<<<128, 256, 0, stream>>>(wk_w, qw, u);
  k_ag<<<dim3(6, 32), 256, 0, stream>>>(ap, w_ih, b_gru, ag);

  for (int chunk = 0; chunk < NCH_; ++chunk) {
    k_gemm_xg<<<dim3(24, 32), 256, 0, stream>>>(tidx, embed, w_ih, ag, xgbuf, chunk);
    int ch = chunk;
    void* args[] = { (void*)&whhT, (void*)&xgbuf, (void*)&hA64, (void*)&hB64,
                     (void*)&hs, (void*)&ch };
    hipLaunchCooperativeKernel((const void*)k_gru_chunk, dim3(256), dim3(512),
                               args, 0, stream);
  }

  k_logits<<<8192, 256, 0, stream>>>(hs, u, lg);
  k_softmax_pool<<<B_, 256, 0, stream>>>(lg, hs, pooled);
  k_dense<<<B_, 64, 0, stream>>>(pooled, dw, db, out);
}